// Round 20
// baseline (155.058 us; speedup 1.0000x reference)
//
#include <hip/hip_runtime.h>
#include <hip/hip_bf16.h>

typedef __attribute__((ext_vector_type(8))) short bf16x8;
typedef __attribute__((ext_vector_type(4))) float f32x4;

struct bf16x8_s { __hip_bfloat16 h[8]; };
struct bf16x4_s { __hip_bfloat16 h[4]; };

// ---------------- fp32 -> bf16 conversion (8 elems/thread) ----------------
__global__ void cvt_kernel(const float* __restrict__ in,
                           __hip_bfloat16* __restrict__ out, int n8) {
  int i = blockIdx.x * blockDim.x + threadIdx.x;
  if (i >= n8) return;
  const float4* p = reinterpret_cast<const float4*>(in) + (size_t)i * 2;
  float4 a = p[0], b = p[1];
  bf16x8_s o;
  o.h[0] = __float2bfloat16(a.x); o.h[1] = __float2bfloat16(a.y);
  o.h[2] = __float2bfloat16(a.z); o.h[3] = __float2bfloat16(a.w);
  o.h[4] = __float2bfloat16(b.x); o.h[5] = __float2bfloat16(b.y);
  o.h[6] = __float2bfloat16(b.z); o.h[7] = __float2bfloat16(b.w);
  *reinterpret_cast<bf16x8_s*>(out + (size_t)i * 8) = o;
}

__global__ void cvt4_kernel(const float* __restrict__ w0,
                            const float* __restrict__ w1,
                            const float* __restrict__ w2,
                            const float* __restrict__ w3,
                            __hip_bfloat16* __restrict__ out) {
  const int bid = blockIdx.x;
  const int seg = bid >> 9;
  const int i = (bid & 511) * 256 + threadIdx.x;
  const float* src = seg == 0 ? w0 : seg == 1 ? w1 : seg == 2 ? w2 : w3;
  const float4* p = reinterpret_cast<const float4*>(src) + (size_t)i * 2;
  float4 a = p[0], b = p[1];
  bf16x8_s o;
  o.h[0] = __float2bfloat16(a.x); o.h[1] = __float2bfloat16(a.y);
  o.h[2] = __float2bfloat16(a.z); o.h[3] = __float2bfloat16(a.w);
  o.h[4] = __float2bfloat16(b.x); o.h[5] = __float2bfloat16(b.y);
  o.h[6] = __float2bfloat16(b.z); o.h[7] = __float2bfloat16(b.w);
  *reinterpret_cast<bf16x8_s*>(out + (size_t)seg * 1048576 + (size_t)i * 8) = o;
}

// ---------------- 128x128 GEMM: A-reuse map + double-buffer rotation -------
// Map (MODE 0): XCD x owns tn in {3x..3x+2}, tn-fast -> A panel L2-filled
// once, W panels L2-resident (R17, FETCH 200->77MB). Schedule: prefetch
// rotation { sync [drains stage(t)]; stage(t+1) other buffer; compute(t) } --
// stage latency hides under a full compute phase (pays now that the fetch
// ceiling is gone). LDS 64 KB (2 buf).
__device__ __forceinline__ void stage_tile(const __hip_bfloat16* src,
                                           char* lds, int tid) {
#pragma unroll
  for (int s = 0; s < 4; ++s) {
    const int c = s * 256 + tid;
    const int row = c >> 3;
    const int cb = (((c & 7) << 4) ^ ((row & 7) << 4));
    __builtin_amdgcn_global_load_lds(
        (const __attribute__((address_space(1))) void*)((const char*)(src + (size_t)row * 1024) + cb),
        (__attribute__((address_space(3))) void*)(lds + s * 4096 + (tid & 192) * 16),
        16, 0, 0);
  }
}

// MODE 0: fused QKV (tn 0..23; sel=tn>>3: Q scaled / K / V-transposed, bf16)
// MODE 1: projection (tn 0..7; fp32 out + bias)
template <int MODE>
__global__ __launch_bounds__(256) void gemm128(
    const __hip_bfloat16* __restrict__ A, const __hip_bfloat16* __restrict__ W,
    const float* __restrict__ b0, const float* __restrict__ b1,
    const float* __restrict__ b2, void* __restrict__ O0,
    void* __restrict__ O1, void* __restrict__ O2) {
  constexpr float SC = 0.18033688011112042f;  // 0.125 * log2(e)
  __shared__ char smem[65536];  // [2][A 16K | W 16K]
  const int tid = threadIdx.x;
  const int lane = tid & 63;
  const int lrow = lane & 15;
  const int lhi = lane >> 4;
  const int wid = tid >> 6;
  const int wm = wid >> 1, wn = wid & 1;
  const int xr = (lrow & 7) << 4;

  const int n = blockIdx.x;
  int tm, tn;
  if constexpr (MODE == 0) {
    const int xcd = n & 7;
    const int u = n >> 3;
    tn = xcd * 3 + u % 3;
    tm = u / 3;
  } else {
    const int wg = (n & 7) * 64 + (n >> 3);
    tm = wg & 63;
    tn = wg >> 6;
  }
  const int row0 = tm * 128;

  const __hip_bfloat16* Ap = A + (size_t)row0 * 1024;
  const __hip_bfloat16* Wp = W + (size_t)(tn * 128) * 1024;

  f32x4 acc[4][4] = {};

  stage_tile(Ap, smem, tid);
  stage_tile(Wp, smem + 16384, tid);
  for (int t = 0; t < 16; ++t) {
    __syncthreads();  // drains stage(t) issued one compute-phase ago
    const char* buf = smem + (t & 1) * 32768;
    if (t + 1 < 16) {
      char* nb = smem + ((t + 1) & 1) * 32768;
      stage_tile(Ap + (t + 1) * 64, nb, tid);
      stage_tile(Wp + (t + 1) * 64, nb + 16384, tid);
    }
    bf16x8 af[4][2], bfr[4][2];
#pragma unroll
    for (int m = 0; m < 4; ++m) {
      const int ar = wm * 64 + m * 16 + lrow;
#pragma unroll
      for (int kk = 0; kk < 2; ++kk)
        af[m][kk] = *reinterpret_cast<const bf16x8*>(
            buf + ar * 128 + ((kk * 64 + lhi * 16) ^ xr));
    }
#pragma unroll
    for (int nn = 0; nn < 4; ++nn) {
      const int br = wn * 64 + nn * 16 + lrow;
#pragma unroll
      for (int kk = 0; kk < 2; ++kk)
        bfr[nn][kk] = *reinterpret_cast<const bf16x8*>(
            buf + 16384 + br * 128 + ((kk * 64 + lhi * 16) ^ xr));
    }
    __builtin_amdgcn_s_setprio(1);
#pragma unroll
    for (int kk = 0; kk < 2; ++kk)
#pragma unroll
      for (int m = 0; m < 4; ++m)
#pragma unroll
        for (int nn = 0; nn < 4; ++nn)
          acc[m][nn] = __builtin_amdgcn_mfma_f32_16x16x32_bf16(
              af[m][kk], bfr[nn][kk], acc[m][nn], 0, 0, 0);
    __builtin_amdgcn_s_setprio(0);
  }

  // ---- epilogue: per-wave 8 KB slice of buf0 (last reads were from buf1;
  // wave-local in-order DS -> no barrier needed)
  char* epi = smem + wid * 8192;
  const int grow0 = row0 + wm * 64;

  if constexpr (MODE == 0) {
    const int sel = tn >> 3;
    const int cloc = (tn & 7) * 128 + wn * 64;
    const float* bias = sel == 0 ? b0 : sel == 1 ? b1 : b2;
    float bv4[4];
#pragma unroll
    for (int nn = 0; nn < 4; ++nn) bv4[nn] = bias[cloc + nn * 16 + lrow];

    if (sel != 2) {
      __hip_bfloat16* dst = sel == 0 ? (__hip_bfloat16*)O0 : (__hip_bfloat16*)O1;
#pragma unroll
      for (int mg = 0; mg < 4; ++mg) {
#pragma unroll
        for (int nn = 0; nn < 4; ++nn)
#pragma unroll
          for (int i = 0; i < 4; ++i) {
            float v = acc[mg][nn][i] + bv4[nn];
            if (sel == 0) v *= SC;
            ((__hip_bfloat16*)epi)[(lhi * 4 + i) * 72 + nn * 16 + lrow] =
                __float2bfloat16(v);
          }
#pragma unroll
        for (int ps = 0; ps < 2; ++ps) {
          const int r = ps * 8 + (lane >> 3);
          bf16x8 val = *reinterpret_cast<const bf16x8*>(epi + r * 144 + (lane & 7) * 16);
          const int grow = grow0 + mg * 16 + r;
          *reinterpret_cast<bf16x8*>(&dst[(size_t)grow * 1024 + cloc + (lane & 7) * 8]) = val;
        }
      }
    } else {
      __hip_bfloat16* dst = (__hip_bfloat16*)O2;
      const int h = cloc >> 6;
      const int bb = grow0 >> 11;
      const int t0 = grow0 & 2047;
      __hip_bfloat16* vb = dst + ((size_t)(bb * 16 + h) * 64) * 2048;
#pragma unroll
      for (int ng = 0; ng < 4; ++ng) {
#pragma unroll
        for (int m = 0; m < 4; ++m)
#pragma unroll
          for (int i = 0; i < 4; ++i) {
            const float v = acc[m][ng][i] + bv4[ng];
            ((__hip_bfloat16*)epi)[lrow * 72 + m * 16 + lhi * 4 + i] =
                __float2bfloat16(v);
          }
#pragma unroll
        for (int ps = 0; ps < 2; ++ps) {
          const int dr = ps * 8 + (lane >> 3);
          bf16x8 val = *reinterpret_cast<const bf16x8*>(epi + dr * 144 + (lane & 7) * 16);
          const int d = ng * 16 + dr;
          *reinterpret_cast<bf16x8*>(&vb[(size_t)d * 2048 + t0 + (lane & 7) * 8]) = val;
        }
      }
    }
  } else {
    float* dst = (float*)O0;
    const int cloc = tn * 128 + wn * 64;
    float bv4[4];
#pragma unroll
    for (int nn = 0; nn < 4; ++nn) bv4[nn] = b0[cloc + nn * 16 + lrow];
#pragma unroll
    for (int mg = 0; mg < 4; ++mg) {
#pragma unroll
      for (int nn = 0; nn < 4; ++nn)
#pragma unroll
        for (int i = 0; i < 4; ++i)
          ((float*)epi)[(lhi * 4 + i) * 68 + nn * 16 + lrow] =
              acc[mg][nn][i] + bv4[nn];
#pragma unroll
      for (int ps = 0; ps < 4; ++ps) {
        const int r = ps * 4 + (lane >> 4);
        float4 val = *reinterpret_cast<const float4*>(epi + r * 272 + (lane & 15) * 16);
        const int grow = grow0 + mg * 16 + r;
        *reinterpret_cast<float4*>(&dst[(size_t)grow * 1024 + cloc + (lane & 15) * 4]) = val;
      }
    }
  }
}

// ---------------- flash attention: 2-frag, shift-free softmax --------------
// (byte-identical to R18)
__device__ __forceinline__ void stage_kv(char* __restrict__ smem, int buf,
                                         const __hip_bfloat16* __restrict__ Kb,
                                         const __hip_bfloat16* __restrict__ Vb,
                                         int kv0, int tid) {
  const int w = tid >> 6, l = tid & 63;
  char* base = smem + buf * 16384;
#pragma unroll
  for (int s = 0; s < 2; ++s) {
    const int c = s * 256 + w * 64 + l;
    const int row = c >> 3;
    const int scb = ((c & 7) << 4) ^ ((row & 7) << 4);
    __builtin_amdgcn_global_load_lds(
        (const __attribute__((address_space(1))) void*)(Kb + (size_t)(kv0 + row) * 1024 + (scb >> 1)),
        (__attribute__((address_space(3))) void*)(base + s * 4096 + w * 1024), 16, 0, 0);
  }
#pragma unroll
  for (int s = 0; s < 2; ++s) {
    const int c = s * 256 + w * 64 + l;
    const int row = c >> 3;
    const int scb = ((c & 7) << 4) ^ ((row & 7) << 4);
    __builtin_amdgcn_global_load_lds(
        (const __attribute__((address_space(1))) void*)(Vb + (size_t)row * 2048 + kv0 + (scb >> 1)),
        (__attribute__((address_space(3))) void*)(base + 8192 + s * 4096 + w * 1024), 16, 0, 0);
  }
}

template <bool MASKED>
__device__ __forceinline__ void attn_step(
    int kv0, int q0w, int lrow, int lhi, const char* __restrict__ kvb,
    const bf16x8 qf[2][2], f32x4 o[2][4], float lp[2],
    char* __restrict__ Pw) {
  const int xr = (lrow & 7) << 4;
  f32x4 s[2][4] = {};
  __builtin_amdgcn_s_setprio(1);
#pragma unroll
  for (int g = 0; g < 4; ++g) {
    const char* rowp = kvb + (g * 16 + lrow) * 128;
#pragma unroll
    for (int kk = 0; kk < 2; ++kk) {
      bf16x8 kf = *reinterpret_cast<const bf16x8*>(rowp + ((kk * 64 + lhi * 16) ^ xr));
#pragma unroll
      for (int j = 0; j < 2; ++j)
        s[j][g] = __builtin_amdgcn_mfma_f32_16x16x32_bf16(kf, qf[j][kk], s[j][g], 0, 0, 0);
    }
  }
  __builtin_amdgcn_s_setprio(0);
  if (MASKED) {
#pragma unroll
    for (int j = 0; j < 2; ++j)
#pragma unroll
      for (int g = 0; g < 4; ++g)
#pragma unroll
        for (int i = 0; i < 4; ++i) {
          const int k = kv0 + g * 16 + lhi * 4 + i;
          if (k > q0w + j * 16 + lrow) s[j][g][i] = -1e30f;
        }
  }
  bf16x8 pf[2][2];
#pragma unroll
  for (int j = 0; j < 2; ++j) {
    float gs[4];
#pragma unroll
    for (int g = 0; g < 4; ++g) {
      bf16x4_s t4;
      float p0 = exp2f(s[j][g][0]);
      float p1 = exp2f(s[j][g][1]);
      float p2 = exp2f(s[j][g][2]);
      float p3 = exp2f(s[j][g][3]);
      t4.h[0] = __float2bfloat16(p0); t4.h[1] = __float2bfloat16(p1);
      t4.h[2] = __float2bfloat16(p2); t4.h[3] = __float2bfloat16(p3);
      gs[g] = (p0 + p1) + (p2 + p3);
      *reinterpret_cast<bf16x4_s*>(Pw + lrow * 128 + ((g * 32 + lhi * 8) ^ xr)) = t4;
    }
    lp[j] += (gs[0] + gs[1]) + (gs[2] + gs[3]);
#pragma unroll
    for (int nn = 0; nn < 2; ++nn)
      pf[j][nn] = *reinterpret_cast<const bf16x8*>(
          Pw + lrow * 128 + ((nn * 64 + lhi * 16) ^ xr));
  }
  __builtin_amdgcn_s_setprio(1);
#pragma unroll
  for (int nn = 0; nn < 2; ++nn)
#pragma unroll
    for (int f = 0; f < 4; ++f) {
      bf16x8 vf = *reinterpret_cast<const bf16x8*>(
          kvb + 8192 + (f * 16 + lrow) * 128 + ((nn * 64 + lhi * 16) ^ xr));
#pragma unroll
      for (int j = 0; j < 2; ++j)
        o[j][f] = __builtin_amdgcn_mfma_f32_16x16x32_bf16(pf[j][nn], vf, o[j][f], 0, 0, 0);
    }
  __builtin_amdgcn_s_setprio(0);
}

__global__ __launch_bounds__(256, 4) void attn_fwd(
    const __hip_bfloat16* __restrict__ Q, const __hip_bfloat16* __restrict__ Km,
    const __hip_bfloat16* __restrict__ Vt, __hip_bfloat16* __restrict__ Y) {
  constexpr int T = 2048, C = 1024, D = 64;
  const int tid = threadIdx.x;
  const int wid = tid >> 6;
  const int lane = tid & 63;
  const int lrow = lane & 15;
  const int lhi = lane >> 4;
  const int n = blockIdx.x;
  const int xcd = n & 7;
  const int w8 = n >> 3;
  const int j2 = w8 >> 5;
  const int r = w8 & 31;
  const int s5 = r >> 3;
  const int bh = xcd * 8 + (r & 7);
  int p;
  if (j2 == 0) p = s5;
  else if (j2 == 1) p = 3 - s5;
  else if (j2 == 2) p = s5 ^ 1;
  else p = 3 - (s5 ^ 1);
  const int qt = 15 - (j2 * 4 + p);
  const int b = bh >> 4, h = bh & 15;
  const int q0w = qt * 128 + wid * 32;

  const __hip_bfloat16* Qb = Q + ((size_t)b * T) * C + h * D;
  const __hip_bfloat16* Kb = Km + ((size_t)b * T) * C + h * D;
  const __hip_bfloat16* Vb = Vt + (size_t)bh * D * T;

  __shared__ char smem[40960];
  char* Pw = smem + 32768 + wid * 2048;

  bf16x8 qf[2][2];
#pragma unroll
  for (int j = 0; j < 2; ++j)
#pragma unroll
    for (int kk = 0; kk < 2; ++kk)
      qf[j][kk] = *reinterpret_cast<const bf16x8*>(
          Qb + (size_t)(q0w + j * 16 + lrow) * C + kk * 32 + lhi * 8);

  f32x4 o[2][4] = {};
  float lp[2] = {0.f, 0.f};

  const int nt = 2 * qt + 2;
  const int ns = (q0w >> 6) + 1;

  stage_kv(smem, 0, Kb, Vb, 0, tid);
  for (int t = 0; t < nt; ++t) {
    __syncthreads();
    if (t + 1 < nt) stage_kv(smem, (t + 1) & 1, Kb, Vb, (t + 1) * 64, tid);
    if (t < ns) {
      const char* kvb = smem + (t & 1) * 16384;
      if (t == ns - 1)
        attn_step<true>(t * 64, q0w, lrow, lhi, kvb, qf, o, lp, Pw);
      else
        attn_step<false>(t * 64, q0w, lrow, lhi, kvb, qf, o, lp, Pw);
    }
  }

#pragma unroll
  for (int j = 0; j < 2; ++j) {
    float l = lp[j];
    l += __shfl_xor(l, 16);
    l += __shfl_xor(l, 32);
    float l4[4];
#pragma unroll
    for (int i = 0; i < 4; ++i) l4[i] = __shfl(l, 4 * lhi + i, 16);
#pragma unroll
    for (int f = 0; f < 4; ++f)
#pragma unroll
      for (int i = 0; i < 4; ++i) {
        const int row = q0w + j * 16 + 4 * lhi + i;
        Y[((size_t)b * T + row) * C + h * D + f * 16 + lrow] =
            __float2bfloat16(o[j][f][i] / l4[i]);
      }
  }
}

// ---------------- host launch ----------------------------------------------
extern "C" void kernel_launch(void* const* d_in, const int* in_sizes, int n_in,
                              void* d_out, int out_size, void* d_ws,
                              size_t ws_size, hipStream_t stream) {
  const float* x = (const float*)d_in[0];
  const float* Wq = (const float*)d_in[1];
  const float* bq = (const float*)d_in[2];
  const float* Wk = (const float*)d_in[3];
  const float* bk = (const float*)d_in[4];
  const float* Wv = (const float*)d_in[5];
  const float* bv = (const float*)d_in[6];
  const float* Wp = (const float*)d_in[7];
  const float* bp = (const float*)d_in[8];
  float* out = (float*)d_out;

  __hip_bfloat16* ws = (__hip_bfloat16*)d_ws;
  __hip_bfloat16* xb = ws;                   // 8388608
  __hip_bfloat16* wqb = xb + 8388608;        // 4 x 1048576, contiguous
  __hip_bfloat16* wpb = wqb + 3 * 1048576;
  __hip_bfloat16* Qs = wqb + 4 * 1048576;    // 8388608
  __hip_bfloat16* Ks = Qs + 8388608;
  __hip_bfloat16* Vts = Ks + 8388608;        // V^T: [B*H*64][2048]
  __hip_bfloat16* Ys = Vts + 8388608;        // attn out [B*T][C]

  cvt_kernel<<<4096, 256, 0, stream>>>(x, xb, 1048576);
  cvt4_kernel<<<2048, 256, 0, stream>>>(Wq, Wk, Wv, Wp, wqb);

  gemm128<0><<<dim3(1536), 256, 0, stream>>>(xb, wqb, bq, bk, bv, Qs, Ks, Vts);

  attn_fwd<<<dim3(1024), 256, 0, stream>>>(Qs, Ks, Vts, Ys);

  gemm128<1><<<dim3(512), 256, 0, stream>>>(Ys, wpb, bp, nullptr, nullptr, out,
                                            nullptr, nullptr);
}

// Round 21
// 154.988 us; speedup vs baseline: 1.0004x; 1.0004x over previous
//
#include <hip/hip_runtime.h>
#include <hip/hip_bf16.h>

typedef __attribute__((ext_vector_type(8))) short bf16x8;
typedef __attribute__((ext_vector_type(4))) float f32x4;

struct bf16x8_s { __hip_bfloat16 h[8]; };
struct bf16x4_s { __hip_bfloat16 h[4]; };

#define AS1 __attribute__((address_space(1)))
#define AS3 __attribute__((address_space(3)))

// ---------------- fp32 -> bf16 conversion (8 elems/thread) ----------------
__global__ void cvt_kernel(const float* __restrict__ in,
                           __hip_bfloat16* __restrict__ out, int n8) {
  int i = blockIdx.x * blockDim.x + threadIdx.x;
  if (i >= n8) return;
  const float4* p = reinterpret_cast<const float4*>(in) + (size_t)i * 2;
  float4 a = p[0], b = p[1];
  bf16x8_s o;
  o.h[0] = __float2bfloat16(a.x); o.h[1] = __float2bfloat16(a.y);
  o.h[2] = __float2bfloat16(a.z); o.h[3] = __float2bfloat16(a.w);
  o.h[4] = __float2bfloat16(b.x); o.h[5] = __float2bfloat16(b.y);
  o.h[6] = __float2bfloat16(b.z); o.h[7] = __float2bfloat16(b.w);
  *reinterpret_cast<bf16x8_s*>(out + (size_t)i * 8) = o;
}

__global__ void cvt4_kernel(const float* __restrict__ w0,
                            const float* __restrict__ w1,
                            const float* __restrict__ w2,
                            const float* __restrict__ w3,
                            __hip_bfloat16* __restrict__ out) {
  const int bid = blockIdx.x;
  const int seg = bid >> 9;
  const int i = (bid & 511) * 256 + threadIdx.x;
  const float* src = seg == 0 ? w0 : seg == 1 ? w1 : seg == 2 ? w2 : w3;
  const float4* p = reinterpret_cast<const float4*>(src) + (size_t)i * 2;
  float4 a = p[0], b = p[1];
  bf16x8_s o;
  o.h[0] = __float2bfloat16(a.x); o.h[1] = __float2bfloat16(a.y);
  o.h[2] = __float2bfloat16(a.z); o.h[3] = __float2bfloat16(a.w);
  o.h[4] = __float2bfloat16(b.x); o.h[5] = __float2bfloat16(b.y);
  o.h[6] = __float2bfloat16(b.z); o.h[7] = __float2bfloat16(b.w);
  *reinterpret_cast<bf16x8_s*>(out + (size_t)seg * 1048576 + (size_t)i * 8) = o;
}

// ============ 256x256 8-phase counted-vmcnt QKV GEMM (T2+T3+T4+T5) =========
// 512 thr = 8 waves (wm=wid>>2, wn=wid&3); wave out 128x64; BK=64; K=1024.
// LDS 128KB: A[2 dbuf][2 half(128 rows)][64] @0, B same @65536; XOR swizzle
// byte ^= (row&7)<<4 (inverse-swizzled global src + swizzled ds_read).
// Tile t in buf[t&1]. Per tile, 4 phases (C-quadrants (0,0)(0,1)(1,1)(1,0)):
//  ph1: read af0(8)+bf0(4); stage A0(t+1); bar; lgkm0; 16 MFMA; bar
//  ph2: read bf1(4);        stage A1(t+1); ...
//  ph3: read af1(8);        stage B0(t+2); ...
//  ph4: (no reads);         stage B1(t+2); vmcnt(4); bar; 16 MFMA; bar
// WAR ledger: A(t+1) buffer's A last read by tile t-1 ph3 (barrier-sep) OK;
// B(t+2) goes into the CURRENT buffer's B region, last read this tile ph2 OK.
// vmcnt(4) FIFO: keeps only B(t+2) in flight; certifies A(t+1)+B(t+1) before
// tile t+1 ph1. Prologue: A(0),B(0),B(1) staged, vmcnt(4). t=14: vmcnt(0).
__device__ __forceinline__ void stage_half256(const __hip_bfloat16* src,
                                              char* dstbase, int tid) {
#pragma unroll
  for (int s = 0; s < 2; ++s) {
    const int c = s * 512 + tid;
    const int r = c >> 3;
    const int cb = ((c & 7) << 4) ^ ((r & 7) << 4);
    __builtin_amdgcn_global_load_lds(
        (const AS1 void*)((const char*)(src + (size_t)r * 1024) + cb),
        (AS3 void*)(dstbase + s * 8192 + (tid & 448) * 16), 16, 0, 0);
  }
}

__global__ __launch_bounds__(512, 1) void gemm256_qkv(
    const __hip_bfloat16* __restrict__ A, const __hip_bfloat16* __restrict__ W,
    const float* __restrict__ bq, const float* __restrict__ bk,
    const float* __restrict__ bv, __hip_bfloat16* __restrict__ Qs,
    __hip_bfloat16* __restrict__ Ks, __hip_bfloat16* __restrict__ Vts) {
  constexpr float SC = 0.18033688011112042f;  // 0.125 * log2(e)
  __shared__ char smem[131072];
  const int tid = threadIdx.x;
  const int lane = tid & 63;
  const int lrow = lane & 15;
  const int lhi = lane >> 4;
  const int wid = tid >> 6;
  const int wm = wid >> 2;   // 0..1
  const int wn = wid & 3;    // 0..3
  const int xr = (lrow & 7) << 4;

  // XCD x owns tm in {4x..4x+3} (tm-fast, tn-slow): 4 A-panels (2MB) L2-hot,
  // W panel read 4x consecutively.
  const int n = blockIdx.x;
  const int xcd = n & 7;
  const int u = n >> 3;          // 0..47
  const int tn = u >> 2;         // 0..11
  const int tm = xcd * 4 + (u & 3);
  const int row0 = tm * 256;

  const __hip_bfloat16* Ap = A + (size_t)row0 * 1024;
  const __hip_bfloat16* Wp = W + (size_t)(tn * 256) * 1024;

#define ABUF(d, h) (smem + (d) * 32768 + (h) * 16384)
#define BBUF(d, h) (smem + 65536 + (d) * 32768 + (h) * 16384)

  f32x4 acc[8][4] = {};

  // ---- prologue: A0(0) A1(0) B0(0) B1(0) B0(1) B1(1); certify tile 0
  stage_half256(Ap, ABUF(0, 0), tid);
  stage_half256(Ap + 128 * 1024, ABUF(0, 1), tid);
  stage_half256(Wp, BBUF(0, 0), tid);
  stage_half256(Wp + 128 * 1024, BBUF(0, 1), tid);
  stage_half256(Wp + 64, BBUF(1, 0), tid);
  stage_half256(Wp + 128 * 1024 + 64, BBUF(1, 1), tid);
  asm volatile("s_waitcnt vmcnt(4)" ::: "memory");
  __builtin_amdgcn_s_barrier();

  for (int t = 0; t < 16; ++t) {
    const int d = t & 1;
    const char* Ab = ABUF(d, wm);
    const char* Bb = BBUF(d, wn >> 1);
    const int brow0 = (wn & 1) * 64;
    bf16x8 af[4][2], bf0[2][2], bf1[2][2];

    // -------- phase 1: quadrant (0,0)
#pragma unroll
    for (int m = 0; m < 4; ++m)
#pragma unroll
      for (int kk = 0; kk < 2; ++kk)
        af[m][kk] = *reinterpret_cast<const bf16x8*>(
            Ab + (m * 16 + lrow) * 128 + ((kk * 64 + lhi * 16) ^ xr));
#pragma unroll
    for (int nf = 0; nf < 2; ++nf)
#pragma unroll
      for (int kk = 0; kk < 2; ++kk)
        bf0[nf][kk] = *reinterpret_cast<const bf16x8*>(
            Bb + (brow0 + nf * 16 + lrow) * 128 + ((kk * 64 + lhi * 16) ^ xr));
    if (t + 1 < 16) stage_half256(Ap + (t + 1) * 64, ABUF(d ^ 1, 0), tid);
    __builtin_amdgcn_s_barrier();
    asm volatile("s_waitcnt lgkmcnt(0)" ::: "memory");
    __builtin_amdgcn_s_setprio(1);
#pragma unroll
    for (int kk = 0; kk < 2; ++kk)
#pragma unroll
      for (int m = 0; m < 4; ++m)
#pragma unroll
        for (int nf = 0; nf < 2; ++nf)
          acc[m][nf] = __builtin_amdgcn_mfma_f32_16x16x32_bf16(
              af[m][kk], bf0[nf][kk], acc[m][nf], 0, 0, 0);
    __builtin_amdgcn_s_setprio(0);
    __builtin_amdgcn_s_barrier();

    // -------- phase 2: quadrant (0,1)
#pragma unroll
    for (int nf = 0; nf < 2; ++nf)
#pragma unroll
      for (int kk = 0; kk < 2; ++kk)
        bf1[nf][kk] = *reinterpret_cast<const bf16x8*>(
            Bb + (brow0 + 32 + nf * 16 + lrow) * 128 + ((kk * 64 + lhi * 16) ^ xr));
    if (t + 1 < 16)
      stage_half256(Ap + 128 * 1024 + (t + 1) * 64, ABUF(d ^ 1, 1), tid);
    __builtin_amdgcn_s_barrier();
    asm volatile("s_waitcnt lgkmcnt(0)" ::: "memory");
    __builtin_amdgcn_s_setprio(1);
#pragma unroll
    for (int kk = 0; kk < 2; ++kk)
#pragma unroll
      for (int m = 0; m < 4; ++m)
#pragma unroll
        for (int nf = 0; nf < 2; ++nf)
          acc[m][2 + nf] = __builtin_amdgcn_mfma_f32_16x16x32_bf16(
              af[m][kk], bf1[nf][kk], acc[m][2 + nf], 0, 0, 0);
    __builtin_amdgcn_s_setprio(0);
    __builtin_amdgcn_s_barrier();

    // -------- phase 3: quadrant (1,1)
#pragma unroll
    for (int m = 0; m < 4; ++m)
#pragma unroll
      for (int kk = 0; kk < 2; ++kk)
        af[m][kk] = *reinterpret_cast<const bf16x8*>(
            Ab + (64 + m * 16 + lrow) * 128 + ((kk * 64 + lhi * 16) ^ xr));
    if (t + 2 < 16) stage_half256(Wp + (t + 2) * 64, BBUF(d, 0), tid);
    __builtin_amdgcn_s_barrier();
    asm volatile("s_waitcnt lgkmcnt(0)" ::: "memory");
    __builtin_amdgcn_s_setprio(1);
#pragma unroll
    for (int kk = 0; kk < 2; ++kk)
#pragma unroll
      for (int m = 0; m < 4; ++m)
#pragma unroll
        for (int nf = 0; nf < 2; ++nf)
          acc[4 + m][2 + nf] = __builtin_amdgcn_mfma_f32_16x16x32_bf16(
              af[m][kk], bf1[nf][kk], acc[4 + m][2 + nf], 0, 0, 0);
    __builtin_amdgcn_s_setprio(0);
    __builtin_amdgcn_s_barrier();

    // -------- phase 4: quadrant (1,0)
    if (t + 2 < 16)
      stage_half256(Wp + 128 * 1024 + (t + 2) * 64, BBUF(d, 1), tid);
    if (t <= 13) { asm volatile("s_waitcnt vmcnt(4)" ::: "memory"); }
    else         { asm volatile("s_waitcnt vmcnt(0)" ::: "memory"); }
    __builtin_amdgcn_s_barrier();
    asm volatile("s_waitcnt lgkmcnt(0)" ::: "memory");
    __builtin_amdgcn_s_setprio(1);
#pragma unroll
    for (int kk = 0; kk < 2; ++kk)
#pragma unroll
      for (int m = 0; m < 4; ++m)
#pragma unroll
        for (int nf = 0; nf < 2; ++nf)
          acc[4 + m][nf] = __builtin_amdgcn_mfma_f32_16x16x32_bf16(
              af[m][kk], bf0[nf][kk], acc[4 + m][nf], 0, 0, 0);
    __builtin_amdgcn_s_setprio(0);
    __builtin_amdgcn_s_barrier();
  }
  __syncthreads();

  // ---- epilogue: per-wave 8 KB LDS slice -> coalesced 16B stores
  char* epi = smem + wid * 8192;
  const int sel = tn >> 2;                       // 0:Q 1:K 2:V
  const int cloc = (tn & 3) * 256 + wn * 64;     // col in [0,1024)
  const float* bias = sel == 0 ? bq : sel == 1 ? bk : bv;
  float bv4[4];
#pragma unroll
  for (int nn = 0; nn < 4; ++nn) bv4[nn] = bias[cloc + nn * 16 + lrow];

#pragma unroll
  for (int mh = 0; mh < 2; ++mh) {
    const int grow0 = row0 + wm * 128 + mh * 64;
    if (sel != 2) {
      __hip_bfloat16* dst = sel == 0 ? Qs : Ks;
#pragma unroll
      for (int mg = 0; mg < 4; ++mg) {
#pragma unroll
        for (int nn = 0; nn < 4; ++nn)
#pragma unroll
          for (int i = 0; i < 4; ++i) {
            float v = acc[mh * 4 + mg][nn][i] + bv4[nn];
            if (sel == 0) v *= SC;
            ((__hip_bfloat16*)epi)[(lhi * 4 + i) * 72 + nn * 16 + lrow] =
                __float2bfloat16(v);
          }
#pragma unroll
        for (int ps = 0; ps < 2; ++ps) {
          const int r = ps * 8 + (lane >> 3);
          bf16x8 val = *reinterpret_cast<const bf16x8*>(epi + r * 144 + (lane & 7) * 16);
          const int grow = grow0 + mg * 16 + r;
          *reinterpret_cast<bf16x8*>(&dst[(size_t)grow * 1024 + cloc + (lane & 7) * 8]) = val;
        }
      }
    } else {
      const int h = cloc >> 6;
      const int bb = grow0 >> 11;
      const int t0 = grow0 & 2047;
      __hip_bfloat16* vb = Vts + ((size_t)(bb * 16 + h) * 64) * 2048;
#pragma unroll
      for (int ng = 0; ng < 4; ++ng) {
#pragma unroll
        for (int m = 0; m < 4; ++m)
#pragma unroll
          for (int i = 0; i < 4; ++i) {
            const float v = acc[mh * 4 + m][ng][i] + bv4[ng];
            ((__hip_bfloat16*)epi)[lrow * 72 + m * 16 + lhi * 4 + i] =
                __float2bfloat16(v);
          }
#pragma unroll
        for (int ps = 0; ps < 2; ++ps) {
          const int dr = ps * 8 + (lane >> 3);
          bf16x8 val = *reinterpret_cast<const bf16x8*>(epi + dr * 144 + (lane & 7) * 16);
          const int dd = ng * 16 + dr;
          *reinterpret_cast<bf16x8*>(&vb[(size_t)dd * 2048 + t0 + (lane & 7) * 8]) = val;
        }
      }
    }
  }
#undef ABUF
#undef BBUF
}

// ---------------- 128x128 GEMM (R18 single-buffer) -- proj only ------------
__device__ __forceinline__ void stage_tile(const __hip_bfloat16* src,
                                           char* lds, int tid) {
#pragma unroll
  for (int s = 0; s < 4; ++s) {
    const int c = s * 256 + tid;
    const int row = c >> 3;
    const int cb = (((c & 7) << 4) ^ ((row & 7) << 4));
    __builtin_amdgcn_global_load_lds(
        (const AS1 void*)((const char*)(src + (size_t)row * 1024) + cb),
        (AS3 void*)(lds + s * 4096 + (tid & 192) * 16), 16, 0, 0);
  }
}

__global__ __launch_bounds__(256) void gemm_proj(
    const __hip_bfloat16* __restrict__ A, const __hip_bfloat16* __restrict__ W,
    const float* __restrict__ b0, float* __restrict__ dst) {
  __shared__ char smem[32768];
  const int tid = threadIdx.x;
  const int lane = tid & 63;
  const int lrow = lane & 15;
  const int lhi = lane >> 4;
  const int wid = tid >> 6;
  const int wm = wid >> 1, wn = wid & 1;
  const int xr = (lrow & 7) << 4;

  const int n = blockIdx.x;
  const int wg = (n & 7) * 64 + (n >> 3);
  const int tm = wg & 63;
  const int tn = wg >> 6;
  const int row0 = tm * 128;

  const __hip_bfloat16* Ap = A + (size_t)row0 * 1024;
  const __hip_bfloat16* Wp = W + (size_t)(tn * 128) * 1024;

  f32x4 acc[4][4] = {};

  for (int k0 = 0; k0 < 1024; k0 += 64) {
    stage_tile(Ap + k0, smem, tid);
    stage_tile(Wp + k0, smem + 16384, tid);
    __syncthreads();
    bf16x8 af[4][2], bfr[4][2];
#pragma unroll
    for (int m = 0; m < 4; ++m) {
      const int ar = wm * 64 + m * 16 + lrow;
#pragma unroll
      for (int kk = 0; kk < 2; ++kk)
        af[m][kk] = *reinterpret_cast<const bf16x8*>(
            smem + ar * 128 + ((kk * 64 + lhi * 16) ^ xr));
    }
#pragma unroll
    for (int nn = 0; nn < 4; ++nn) {
      const int br = wn * 64 + nn * 16 + lrow;
#pragma unroll
      for (int kk = 0; kk < 2; ++kk)
        bfr[nn][kk] = *reinterpret_cast<const bf16x8*>(
            smem + 16384 + br * 128 + ((kk * 64 + lhi * 16) ^ xr));
    }
    __builtin_amdgcn_s_setprio(1);
#pragma unroll
    for (int kk = 0; kk < 2; ++kk)
#pragma unroll
      for (int m = 0; m < 4; ++m)
#pragma unroll
        for (int nn = 0; nn < 4; ++nn)
          acc[m][nn] = __builtin_amdgcn_mfma_f32_16x16x32_bf16(
              af[m][kk], bfr[nn][kk], acc[m][nn], 0, 0, 0);
    __builtin_amdgcn_s_setprio(0);
    __syncthreads();
  }

  char* epi = smem + wid * 8192;
  const int grow0 = row0 + wm * 64;
  const int cloc = tn * 128 + wn * 64;
  float bv4[4];
#pragma unroll
  for (int nn = 0; nn < 4; ++nn) bv4[nn] = b0[cloc + nn * 16 + lrow];
#pragma unroll
  for (int mg = 0; mg < 4; ++mg) {
#pragma unroll
    for (int nn = 0; nn < 4; ++nn)
#pragma unroll
      for (int i = 0; i < 4; ++i)
        ((float*)epi)[(lhi * 4 + i) * 68 + nn * 16 + lrow] =
            acc[mg][nn][i] + bv4[nn];
#pragma unroll
    for (int ps = 0; ps < 4; ++ps) {
      const int r = ps * 4 + (lane >> 4);
      float4 val = *reinterpret_cast<const float4*>(epi + r * 272 + (lane & 15) * 16);
      const int grow = grow0 + mg * 16 + r;
      *reinterpret_cast<float4*>(&dst[(size_t)grow * 1024 + cloc + (lane & 15) * 4]) = val;
    }
  }
}

// ---------------- flash attention: 2-frag, shift-free softmax (R18) --------
__device__ __forceinline__ void stage_kv(char* __restrict__ smem, int buf,
                                         const __hip_bfloat16* __restrict__ Kb,
                                         const __hip_bfloat16* __restrict__ Vb,
                                         int kv0, int tid) {
  const int w = tid >> 6, l = tid & 63;
  char* base = smem + buf * 16384;
#pragma unroll
  for (int s = 0; s < 2; ++s) {
    const int c = s * 256 + w * 64 + l;
    const int row = c >> 3;
    const int scb = ((c & 7) << 4) ^ ((row & 7) << 4);
    __builtin_amdgcn_global_load_lds(
        (const AS1 void*)(Kb + (size_t)(kv0 + row) * 1024 + (scb >> 1)),
        (AS3 void*)(base + s * 4096 + w * 1024), 16, 0, 0);
  }
#pragma unroll
  for (int s = 0; s < 2; ++s) {
    const int c = s * 256 + w * 64 + l;
    const int row = c >> 3;
    const int scb = ((c & 7) << 4) ^ ((row & 7) << 4);
    __builtin_amdgcn_global_load_lds(
        (const AS1 void*)(Vb + (size_t)row * 2048 + kv0 + (scb >> 1)),
        (AS3 void*)(base + 8192 + s * 4096 + w * 1024), 16, 0, 0);
  }
}

template <bool MASKED>
__device__ __forceinline__ void attn_step(
    int kv0, int q0w, int lrow, int lhi, const char* __restrict__ kvb,
    const bf16x8 qf[2][2], f32x4 o[2][4], float lp[2],
    char* __restrict__ Pw) {
  const int xr = (lrow & 7) << 4;
  f32x4 s[2][4] = {};
  __builtin_amdgcn_s_setprio(1);
#pragma unroll
  for (int g = 0; g < 4; ++g) {
    const char* rowp = kvb + (g * 16 + lrow) * 128;
#pragma unroll
    for (int kk = 0; kk < 2; ++kk) {
      bf16x8 kf = *reinterpret_cast<const bf16x8*>(rowp + ((kk * 64 + lhi * 16) ^ xr));
#pragma unroll
      for (int j = 0; j < 2; ++j)
        s[j][g] = __builtin_amdgcn_mfma_f32_16x16x32_bf16(kf, qf[j][kk], s[j][g], 0, 0, 0);
    }
  }
  __builtin_amdgcn_s_setprio(0);
  if (MASKED) {
#pragma unroll
    for (int j = 0; j < 2; ++j)
#pragma unroll
      for (int g = 0; g < 4; ++g)
#pragma unroll
        for (int i = 0; i < 4; ++i) {
          const int k = kv0 + g * 16 + lhi * 4 + i;
          if (k > q0w + j * 16 + lrow) s[j][g][i] = -1e30f;
        }
  }
  bf16x8 pf[2][2];
#pragma unroll
  for (int j = 0; j < 2; ++j) {
    float gs[4];
#pragma unroll
    for (int g = 0; g < 4; ++g) {
      bf16x4_s t4;
      float p0 = exp2f(s[j][g][0]);
      float p1 = exp2f(s[j][g][1]);
      float p2 = exp2f(s[j][g][2]);
      float p3 = exp2f(s[j][g][3]);
      t4.h[0] = __float2bfloat16(p0); t4.h[1] = __float2bfloat16(p1);
      t4.h[2] = __float2bfloat16(p2); t4.h[3] = __float2bfloat16(p3);
      gs[g] = (p0 + p1) + (p2 + p3);
      *reinterpret_cast<bf16x4_s*>(Pw + lrow * 128 + ((g * 32 + lhi * 8) ^ xr)) = t4;
    }
    lp[j] += (gs[0] + gs[1]) + (gs[2] + gs[3]);
#pragma unroll
    for (int nn = 0; nn < 2; ++nn)
      pf[j][nn] = *reinterpret_cast<const bf16x8*>(
          Pw + lrow * 128 + ((nn * 64 + lhi * 16) ^ xr));
  }
  __builtin_amdgcn_s_setprio(1);
#pragma unroll
  for (int nn = 0; nn < 2; ++nn)
#pragma unroll
    for (int f = 0; f < 4; ++f) {
      bf16x8 vf = *reinterpret_cast<const bf16x8*>(
          kvb + 8192 + (f * 16 + lrow) * 128 + ((nn * 64 + lhi * 16) ^ xr));
#pragma unroll
      for (int j = 0; j < 2; ++j)
        o[j][f] = __builtin_amdgcn_mfma_f32_16x16x32_bf16(pf[j][nn], vf, o[j][f], 0, 0, 0);
    }
  __builtin_amdgcn_s_setprio(0);
}

__global__ __launch_bounds__(256, 4) void attn_fwd(
    const __hip_bfloat16* __restrict__ Q, const __hip_bfloat16* __restrict__ Km,
    const __hip_bfloat16* __restrict__ Vt, __hip_bfloat16* __restrict__ Y) {
  constexpr int T = 2048, C = 1024, D = 64;
  const int tid = threadIdx.x;
  const int wid = tid >> 6;
  const int lane = tid & 63;
  const int lrow = lane & 15;
  const int lhi = lane >> 4;
  const int n = blockIdx.x;
  const int xcd = n & 7;
  const int w8 = n >> 3;
  const int j2 = w8 >> 5;
  const int r = w8 & 31;
  const int s5 = r >> 3;
  const int bh = xcd * 8 + (r & 7);
  int p;
  if (j2 == 0) p = s5;
  else if (j2 == 1) p = 3 - s5;
  else if (j2 == 2) p = s5 ^ 1;
  else p = 3 - (s5 ^ 1);
  const int qt = 15 - (j2 * 4 + p);
  const int b = bh >> 4, h = bh & 15;
  const int q0w = qt * 128 + wid * 32;

  const __hip_bfloat16* Qb = Q + ((size_t)b * T) * C + h * D;
  const __hip_bfloat16* Kb = Km + ((size_t)b * T) * C + h * D;
  const __hip_bfloat16* Vb = Vt + (size_t)bh * D * T;

  __shared__ char smem[40960];
  char* Pw = smem + 32768 + wid * 2048;

  bf16x8 qf[2][2];
#pragma unroll
  for (int j = 0; j < 2; ++j)
#pragma unroll
    for (int kk = 0; kk < 2; ++kk)
      qf[j][kk] = *reinterpret_cast<const bf16x8*>(
          Qb + (size_t)(q0w + j * 16 + lrow) * C + kk * 32 + lhi * 8);

  f32x4 o[2][4] = {};
  float lp[2] = {0.f, 0.f};

  const int nt = 2 * qt + 2;
  const int ns = (q0w >> 6) + 1;

  stage_kv(smem, 0, Kb, Vb, 0, tid);
  for (int t = 0; t < nt; ++t) {
    __syncthreads();
    if (t + 1 < nt) stage_kv(smem, (t + 1) & 1, Kb, Vb, (t + 1) * 64, tid);
    if (t < ns) {
      const char* kvb = smem + (t & 1) * 16384;
      if (t == ns - 1)
        attn_step<true>(t * 64, q0w, lrow, lhi, kvb, qf, o, lp, Pw);
      else
        attn_step<false>(t * 64, q0w, lrow, lhi, kvb, qf, o, lp, Pw);
    }
  }

#pragma unroll
  for (int j = 0; j < 2; ++j) {
    float l = lp[j];
    l += __shfl_xor(l, 16);
    l += __shfl_xor(l, 32);
    float l4[4];
#pragma unroll
    for (int i = 0; i < 4; ++i) l4[i] = __shfl(l, 4 * lhi + i, 16);
#pragma unroll
    for (int f = 0; f < 4; ++f)
#pragma unroll
      for (int i = 0; i < 4; ++i) {
        const int row = q0w + j * 16 + 4 * lhi + i;
        Y[((size_t)b * T + row) * C + h * D + f * 16 + lrow] =
            __float2bfloat16(o[j][f][i] / l4[i]);
      }
  }
}

// ---------------- host launch ----------------------------------------------
extern "C" void kernel_launch(void* const* d_in, const int* in_sizes, int n_in,
                              void* d_out, int out_size, void* d_ws,
                              size_t ws_size, hipStream_t stream) {
  const float* x = (const float*)d_in[0];
  const float* Wq = (const float*)d_in[1];
  const float* bq = (const float*)d_in[2];
  const float* Wk = (const float*)d_in[3];
  const float* bk = (const float*)d_in[4];
  const float* Wv = (const float*)d_in[5];
  const float* bv = (const float*)d_in[6];
  const float* Wp = (const float*)d_in[7];
  const float* bp = (const float*)d_in[8];
  float* out = (float*)d_out;

  __hip_bfloat16* ws = (__hip_bfloat16*)d_ws;
  __hip_bfloat16* xb = ws;                   // 8388608
  __hip_bfloat16* wqb = xb + 8388608;        // 4 x 1048576, contiguous
  __hip_bfloat16* wpb = wqb + 3 * 1048576;
  __hip_bfloat16* Qs = wqb + 4 * 1048576;    // 8388608
  __hip_bfloat16* Ks = Qs + 8388608;
  __hip_bfloat16* Vts = Ks + 8388608;        // V^T: [B*H*64][2048]
  __hip_bfloat16* Ys = Vts + 8388608;        // attn out [B*T][C]

  cvt_kernel<<<4096, 256, 0, stream>>>(x, xb, 1048576);
  cvt4_kernel<<<2048, 256, 0, stream>>>(Wq, Wk, Wv, Wp, wqb);

  // QKV: 32 tm x 12 tn = 384 blocks, 512 threads (8-phase 256^2)
  gemm256_qkv<<<dim3(384), 512, 0, stream>>>(xb, wqb, bq, bk, bv, Qs, Ks, Vts);

  attn_fwd<<<dim3(1024), 256, 0, stream>>>(Qs, Ks, Vts, Ys);

  gemm_proj<<<dim3(512), 256, 0, stream>>>(Ys, wpb, bp, out);
}

// Round 22
// 151.000 us; speedup vs baseline: 1.0269x; 1.0264x over previous
//
#include <hip/hip_runtime.h>
#include <hip/hip_bf16.h>

typedef __attribute__((ext_vector_type(8))) short bf16x8;
typedef __attribute__((ext_vector_type(4))) float f32x4;

struct bf16x8_s { __hip_bfloat16 h[8]; };
struct bf16x4_s { __hip_bfloat16 h[4]; };

#define AS1 __attribute__((address_space(1)))
#define AS3 __attribute__((address_space(3)))

// ------- fp32 -> bf16 conversion, x + all 4 weights in ONE dispatch --------
// bid < 4096: x (4096*256*8 = 8388608 elems). bid >= 4096: weight seg.
__global__ void cvt_all(const float* __restrict__ x,
                        const float* __restrict__ w0,
                        const float* __restrict__ w1,
                        const float* __restrict__ w2,
                        const float* __restrict__ w3,
                        __hip_bfloat16* __restrict__ xb,
                        __hip_bfloat16* __restrict__ wb) {
  const int bid = blockIdx.x;
  const float* src;
  __hip_bfloat16* dst;
  size_t i;
  if (bid < 4096) {
    src = x;
    dst = xb;
    i = (size_t)bid * 256 + threadIdx.x;
  } else {
    const int wb4 = bid - 4096;           // 0..2047
    const int seg = wb4 >> 9;             // 0..3
    src = seg == 0 ? w0 : seg == 1 ? w1 : seg == 2 ? w2 : w3;
    dst = wb + (size_t)seg * 1048576;
    i = (size_t)(wb4 & 511) * 256 + threadIdx.x;
  }
  const float4* p = reinterpret_cast<const float4*>(src) + i * 2;
  float4 a = p[0], b = p[1];
  bf16x8_s o;
  o.h[0] = __float2bfloat16(a.x); o.h[1] = __float2bfloat16(a.y);
  o.h[2] = __float2bfloat16(a.z); o.h[3] = __float2bfloat16(a.w);
  o.h[4] = __float2bfloat16(b.x); o.h[5] = __float2bfloat16(b.y);
  o.h[6] = __float2bfloat16(b.z); o.h[7] = __float2bfloat16(b.w);
  *reinterpret_cast<bf16x8_s*>(dst + i * 8) = o;
}

// ---------------- 128x128 GEMM (m97 structure + T2 swizzle + coalesced epi) -
// MODE 0 block map is A-REUSE ordered (R17): tn-fast within XCD -> A panel
// L2-filled once, W panels L2-resident.
__device__ __forceinline__ void stage_tile(const __hip_bfloat16* src,
                                           char* lds, int tid) {
#pragma unroll
  for (int s = 0; s < 4; ++s) {
    const int c = s * 256 + tid;
    const int row = c >> 3;
    const int cb = (((c & 7) << 4) ^ ((row & 7) << 4));
    __builtin_amdgcn_global_load_lds(
        (const AS1 void*)((const char*)(src + (size_t)row * 1024) + cb),
        (AS3 void*)(lds + s * 4096 + (tid & 192) * 16), 16, 0, 0);
  }
}

// MODE 0: fused QKV (tn 0..23; sel=tn>>3: Q scaled / K / V-transposed, bf16)
// MODE 1: projection (tn 0..7; fp32 out + bias)
template <int MODE>
__global__ __launch_bounds__(256) void gemm128(
    const __hip_bfloat16* __restrict__ A, const __hip_bfloat16* __restrict__ W,
    const float* __restrict__ b0, const float* __restrict__ b1,
    const float* __restrict__ b2, void* __restrict__ O0,
    void* __restrict__ O1, void* __restrict__ O2) {
  constexpr float SC = 0.18033688011112042f;  // 0.125 * log2(e)
  __shared__ char smem[32768];
  const int tid = threadIdx.x;
  const int lane = tid & 63;
  const int lrow = lane & 15;
  const int lhi = lane >> 4;
  const int wid = tid >> 6;
  const int wm = wid >> 1, wn = wid & 1;
  const int xr = (lrow & 7) << 4;

  const int n = blockIdx.x;
  int tm, tn;
  if constexpr (MODE == 0) {
    const int xcd = n & 7;
    const int u = n >> 3;
    tn = xcd * 3 + u % 3;
    tm = u / 3;
  } else {
    const int wg = (n & 7) * 64 + (n >> 3);
    tm = wg & 63;
    tn = wg >> 6;
  }
  const int row0 = tm * 128;

  const __hip_bfloat16* Ap = A + (size_t)row0 * 1024;
  const __hip_bfloat16* Wp = W + (size_t)(tn * 128) * 1024;

  f32x4 acc[4][4] = {};

  for (int k0 = 0; k0 < 1024; k0 += 64) {
    stage_tile(Ap + k0, smem, tid);
    stage_tile(Wp + k0, smem + 16384, tid);
    __syncthreads();
    bf16x8 af[4][2], bfr[4][2];
#pragma unroll
    for (int m = 0; m < 4; ++m) {
      const int ar = wm * 64 + m * 16 + lrow;
#pragma unroll
      for (int kk = 0; kk < 2; ++kk)
        af[m][kk] = *reinterpret_cast<const bf16x8*>(
            smem + ar * 128 + ((kk * 64 + lhi * 16) ^ xr));
    }
#pragma unroll
    for (int nn = 0; nn < 4; ++nn) {
      const int br = wn * 64 + nn * 16 + lrow;
#pragma unroll
      for (int kk = 0; kk < 2; ++kk)
        bfr[nn][kk] = *reinterpret_cast<const bf16x8*>(
            smem + 16384 + br * 128 + ((kk * 64 + lhi * 16) ^ xr));
    }
    __builtin_amdgcn_s_setprio(1);
#pragma unroll
    for (int kk = 0; kk < 2; ++kk)
#pragma unroll
      for (int m = 0; m < 4; ++m)
#pragma unroll
        for (int nn = 0; nn < 4; ++nn)
          acc[m][nn] = __builtin_amdgcn_mfma_f32_16x16x32_bf16(
              af[m][kk], bfr[nn][kk], acc[m][nn], 0, 0, 0);
    __builtin_amdgcn_s_setprio(0);
    __syncthreads();
  }

  // ---- epilogue: per-wave 8 KB LDS slice -> coalesced 16B stores
  char* epi = smem + wid * 8192;
  const int grow0 = row0 + wm * 64;

  if constexpr (MODE == 0) {
    const int sel = tn >> 3;
    const int cloc = (tn & 7) * 128 + wn * 64;
    const float* bias = sel == 0 ? b0 : sel == 1 ? b1 : b2;
    float bv4[4];
#pragma unroll
    for (int nn = 0; nn < 4; ++nn) bv4[nn] = bias[cloc + nn * 16 + lrow];

    if (sel != 2) {
      __hip_bfloat16* dst = sel == 0 ? (__hip_bfloat16*)O0 : (__hip_bfloat16*)O1;
#pragma unroll
      for (int mg = 0; mg < 4; ++mg) {
#pragma unroll
        for (int nn = 0; nn < 4; ++nn)
#pragma unroll
          for (int i = 0; i < 4; ++i) {
            float v = acc[mg][nn][i] + bv4[nn];
            if (sel == 0) v *= SC;
            ((__hip_bfloat16*)epi)[(lhi * 4 + i) * 72 + nn * 16 + lrow] =
                __float2bfloat16(v);
          }
#pragma unroll
        for (int ps = 0; ps < 2; ++ps) {
          const int r = ps * 8 + (lane >> 3);
          bf16x8 val = *reinterpret_cast<const bf16x8*>(epi + r * 144 + (lane & 7) * 16);
          const int grow = grow0 + mg * 16 + r;
          *reinterpret_cast<bf16x8*>(&dst[(size_t)grow * 1024 + cloc + (lane & 7) * 8]) = val;
        }
      }
    } else {
      __hip_bfloat16* dst = (__hip_bfloat16*)O2;
      const int h = cloc >> 6;
      const int bb = grow0 >> 11;
      const int t0 = grow0 & 2047;
      __hip_bfloat16* vb = dst + ((size_t)(bb * 16 + h) * 64) * 2048;
#pragma unroll
      for (int ng = 0; ng < 4; ++ng) {
#pragma unroll
        for (int m = 0; m < 4; ++m)
#pragma unroll
          for (int i = 0; i < 4; ++i) {
            const float v = acc[m][ng][i] + bv4[ng];
            ((__hip_bfloat16*)epi)[lrow * 72 + m * 16 + lhi * 4 + i] =
                __float2bfloat16(v);
          }
#pragma unroll
        for (int ps = 0; ps < 2; ++ps) {
          const int dr = ps * 8 + (lane >> 3);
          bf16x8 val = *reinterpret_cast<const bf16x8*>(epi + dr * 144 + (lane & 7) * 16);
          const int d = ng * 16 + dr;
          *reinterpret_cast<bf16x8*>(&vb[(size_t)d * 2048 + t0 + (lane & 7) * 8]) = val;
        }
      }
    }
  } else {
    float* dst = (float*)O0;
    const int cloc = tn * 128 + wn * 64;
    float bv4[4];
#pragma unroll
    for (int nn = 0; nn < 4; ++nn) bv4[nn] = b0[cloc + nn * 16 + lrow];
#pragma unroll
    for (int mg = 0; mg < 4; ++mg) {
#pragma unroll
      for (int nn = 0; nn < 4; ++nn)
#pragma unroll
        for (int i = 0; i < 4; ++i)
          ((float*)epi)[(lhi * 4 + i) * 68 + nn * 16 + lrow] =
              acc[mg][nn][i] + bv4[nn];
#pragma unroll
      for (int ps = 0; ps < 4; ++ps) {
        const int r = ps * 4 + (lane >> 4);
        float4 val = *reinterpret_cast<const float4*>(epi + r * 272 + (lane & 15) * 16);
        const int grow = grow0 + mg * 16 + r;
        *reinterpret_cast<float4*>(&dst[(size_t)grow * 1024 + cloc + (lane & 15) * 4]) = val;
      }
    }
  }
}

// ---------------- flash attention: 2-frag, shift-free softmax --------------
// P = exp2(s) raw (shift-invariant ratio); per-lane l partials, one
// end-of-kernel reduction; XOR-swizzled KV staging; 40960 B LDS -> 4 blk/CU.
__device__ __forceinline__ void stage_kv(char* __restrict__ smem, int buf,
                                         const __hip_bfloat16* __restrict__ Kb,
                                         const __hip_bfloat16* __restrict__ Vb,
                                         int kv0, int tid) {
  const int w = tid >> 6, l = tid & 63;
  char* base = smem + buf * 16384;
#pragma unroll
  for (int s = 0; s < 2; ++s) {
    const int c = s * 256 + w * 64 + l;
    const int row = c >> 3;
    const int scb = ((c & 7) << 4) ^ ((row & 7) << 4);
    __builtin_amdgcn_global_load_lds(
        (const AS1 void*)(Kb + (size_t)(kv0 + row) * 1024 + (scb >> 1)),
        (AS3 void*)(base + s * 4096 + w * 1024), 16, 0, 0);
  }
#pragma unroll
  for (int s = 0; s < 2; ++s) {
    const int c = s * 256 + w * 64 + l;
    const int row = c >> 3;
    const int scb = ((c & 7) << 4) ^ ((row & 7) << 4);
    __builtin_amdgcn_global_load_lds(
        (const AS1 void*)(Vb + (size_t)row * 2048 + kv0 + (scb >> 1)),
        (AS3 void*)(base + 8192 + s * 4096 + w * 1024), 16, 0, 0);
  }
}

template <bool MASKED>
__device__ __forceinline__ void attn_step(
    int kv0, int q0w, int lrow, int lhi, const char* __restrict__ kvb,
    const bf16x8 qf[2][2], f32x4 o[2][4], float lp[2],
    char* __restrict__ Pw) {
  const int xr = (lrow & 7) << 4;
  f32x4 s[2][4] = {};
  __builtin_amdgcn_s_setprio(1);
#pragma unroll
  for (int g = 0; g < 4; ++g) {
    const char* rowp = kvb + (g * 16 + lrow) * 128;
#pragma unroll
    for (int kk = 0; kk < 2; ++kk) {
      bf16x8 kf = *reinterpret_cast<const bf16x8*>(rowp + ((kk * 64 + lhi * 16) ^ xr));
#pragma unroll
      for (int j = 0; j < 2; ++j)
        s[j][g] = __builtin_amdgcn_mfma_f32_16x16x32_bf16(kf, qf[j][kk], s[j][g], 0, 0, 0);
    }
  }
  __builtin_amdgcn_s_setprio(0);
  if (MASKED) {
#pragma unroll
    for (int j = 0; j < 2; ++j)
#pragma unroll
      for (int g = 0; g < 4; ++g)
#pragma unroll
        for (int i = 0; i < 4; ++i) {
          const int k = kv0 + g * 16 + lhi * 4 + i;
          if (k > q0w + j * 16 + lrow) s[j][g][i] = -1e30f;
        }
  }
  bf16x8 pf[2][2];
#pragma unroll
  for (int j = 0; j < 2; ++j) {
    float gs[4];
#pragma unroll
    for (int g = 0; g < 4; ++g) {
      bf16x4_s t4;
      float p0 = exp2f(s[j][g][0]);
      float p1 = exp2f(s[j][g][1]);
      float p2 = exp2f(s[j][g][2]);
      float p3 = exp2f(s[j][g][3]);
      t4.h[0] = __float2bfloat16(p0); t4.h[1] = __float2bfloat16(p1);
      t4.h[2] = __float2bfloat16(p2); t4.h[3] = __float2bfloat16(p3);
      gs[g] = (p0 + p1) + (p2 + p3);
      *reinterpret_cast<bf16x4_s*>(Pw + lrow * 128 + ((g * 32 + lhi * 8) ^ xr)) = t4;
    }
    lp[j] += (gs[0] + gs[1]) + (gs[2] + gs[3]);
#pragma unroll
    for (int nn = 0; nn < 2; ++nn)
      pf[j][nn] = *reinterpret_cast<const bf16x8*>(
          Pw + lrow * 128 + ((nn * 64 + lhi * 16) ^ xr));
  }
  __builtin_amdgcn_s_setprio(1);
#pragma unroll
  for (int nn = 0; nn < 2; ++nn)
#pragma unroll
    for (int f = 0; f < 4; ++f) {
      bf16x8 vf = *reinterpret_cast<const bf16x8*>(
          kvb + 8192 + (f * 16 + lrow) * 128 + ((nn * 64 + lhi * 16) ^ xr));
#pragma unroll
      for (int j = 0; j < 2; ++j)
        o[j][f] = __builtin_amdgcn_mfma_f32_16x16x32_bf16(pf[j][nn], vf, o[j][f], 0, 0, 0);
    }
  __builtin_amdgcn_s_setprio(0);
}

__global__ __launch_bounds__(256, 4) void attn_fwd(
    const __hip_bfloat16* __restrict__ Q, const __hip_bfloat16* __restrict__ Km,
    const __hip_bfloat16* __restrict__ Vt, __hip_bfloat16* __restrict__ Y) {
  constexpr int T = 2048, C = 1024, D = 64;
  const int tid = threadIdx.x;
  const int wid = tid >> 6;
  const int lane = tid & 63;
  const int lrow = lane & 15;
  const int lhi = lane >> 4;
  const int n = blockIdx.x;
  const int xcd = n & 7;
  const int w8 = n >> 3;
  const int j2 = w8 >> 5;
  const int r = w8 & 31;
  const int s5 = r >> 3;
  const int bh = xcd * 8 + (r & 7);
  int p;
  if (j2 == 0) p = s5;
  else if (j2 == 1) p = 3 - s5;
  else if (j2 == 2) p = s5 ^ 1;
  else p = 3 - (s5 ^ 1);
  const int qt = 15 - (j2 * 4 + p);
  const int b = bh >> 4, h = bh & 15;
  const int q0w = qt * 128 + wid * 32;

  const __hip_bfloat16* Qb = Q + ((size_t)b * T) * C + h * D;
  const __hip_bfloat16* Kb = Km + ((size_t)b * T) * C + h * D;
  const __hip_bfloat16* Vb = Vt + (size_t)bh * D * T;

  __shared__ char smem[40960];
  char* Pw = smem + 32768 + wid * 2048;

  bf16x8 qf[2][2];
#pragma unroll
  for (int j = 0; j < 2; ++j)
#pragma unroll
    for (int kk = 0; kk < 2; ++kk)
      qf[j][kk] = *reinterpret_cast<const bf16x8*>(
          Qb + (size_t)(q0w + j * 16 + lrow) * C + kk * 32 + lhi * 8);

  f32x4 o[2][4] = {};
  float lp[2] = {0.f, 0.f};

  const int nt = 2 * qt + 2;
  const int ns = (q0w >> 6) + 1;

  stage_kv(smem, 0, Kb, Vb, 0, tid);
  for (int t = 0; t < nt; ++t) {
    __syncthreads();
    if (t + 1 < nt) stage_kv(smem, (t + 1) & 1, Kb, Vb, (t + 1) * 64, tid);
    if (t < ns) {
      const char* kvb = smem + (t & 1) * 16384;
      if (t == ns - 1)
        attn_step<true>(t * 64, q0w, lrow, lhi, kvb, qf, o, lp, Pw);
      else
        attn_step<false>(t * 64, q0w, lrow, lhi, kvb, qf, o, lp, Pw);
    }
  }

#pragma unroll
  for (int j = 0; j < 2; ++j) {
    float l = lp[j];
    l += __shfl_xor(l, 16);
    l += __shfl_xor(l, 32);
    float l4[4];
#pragma unroll
    for (int i = 0; i < 4; ++i) l4[i] = __shfl(l, 4 * lhi + i, 16);
#pragma unroll
    for (int f = 0; f < 4; ++f)
#pragma unroll
      for (int i = 0; i < 4; ++i) {
        const int row = q0w + j * 16 + 4 * lhi + i;
        Y[((size_t)b * T + row) * C + h * D + f * 16 + lrow] =
            __float2bfloat16(o[j][f][i] / l4[i]);
      }
  }
}

// ---------------- host launch ----------------------------------------------
extern "C" void kernel_launch(void* const* d_in, const int* in_sizes, int n_in,
                              void* d_out, int out_size, void* d_ws,
                              size_t ws_size, hipStream_t stream) {
  const float* x = (const float*)d_in[0];
  const float* Wq = (const float*)d_in[1];
  const float* bq = (const float*)d_in[2];
  const float* Wk = (const float*)d_in[3];
  const float* bk = (const float*)d_in[4];
  const float* Wv = (const float*)d_in[5];
  const float* bv = (const float*)d_in[6];
  const float* Wp = (const float*)d_in[7];
  const float* bp = (const float*)d_in[8];
  float* out = (float*)d_out;

  __hip_bfloat16* ws = (__hip_bfloat16*)d_ws;
  __hip_bfloat16* xb = ws;                   // 8388608
  __hip_bfloat16* wqb = xb + 8388608;        // 4 x 1048576, contiguous
  __hip_bfloat16* wpb = wqb + 3 * 1048576;
  __hip_bfloat16* Qs = wqb + 4 * 1048576;    // 8388608
  __hip_bfloat16* Ks = Qs + 8388608;
  __hip_bfloat16* Vts = Ks + 8388608;        // V^T: [B*H*64][2048]
  __hip_bfloat16* Ys = Vts + 8388608;        // attn out [B*T][C]

  cvt_all<<<6144, 256, 0, stream>>>(x, Wq, Wk, Wv, Wp, xb, wqb);

  gemm128<0><<<dim3(1536), 256, 0, stream>>>(xb, wqb, bq, bk, bv, Qs, Ks, Vts);

  attn_fwd<<<dim3(1024), 256, 0, stream>>>(Qs, Ks, Vts, Ys);

  gemm128<1><<<dim3(512), 256, 0, stream>>>(Ys, wpb, bp, nullptr, nullptr, out,
                                            nullptr, nullptr);
}